// Round 1
// baseline (468.697 us; speedup 1.0000x reference)
//
#include <hip/hip_runtime.h>
#include <cstdint>

#define NSTEP 1000
#define NELEM 45056          // 16 * 1 * 64 * 44
#define HW    2816           // 64 * 44

// ---------- compile-time fp64 DDIM schedule (bit-exact vs np.linspace+cumprod) ----------
struct AlphTab { float a[NSTEP + 1]; };

constexpr AlphTab make_alph() {
    AlphTab t{};
    t.a[0] = 1.0f;
    double alph = 1.0;
    const double start = 1e-4, stop = 0.02;
    const double step = (stop - start) / 999.0;   // np.linspace step in f64
    for (int i = 0; i < NSTEP; ++i) {
        double beta = (i == NSTEP - 1) ? stop : ((double)i * step + start); // y[-1]=stop
        alph *= (1.0 - beta);
        t.a[i + 1] = (float)alph;                 // astype(float32)
    }
    return t;
}
constexpr AlphTab ALPH = make_alph();

// ---------- Threefry-2x32-20 (jax threefry2x32_p) ----------
__device__ __forceinline__ void tf20(uint32_t K0, uint32_t K1, uint32_t K2,
                                     uint32_t& x0, uint32_t& x1) {
    x0 += K0; x1 += K1;
#define TFR(r) { x0 += x1; x1 = ((x1 << r) | (x1 >> (32 - r))); x1 ^= x0; }
    TFR(13) TFR(15) TFR(26) TFR(6)
    x0 += K1; x1 += K2 + 1u;
    TFR(17) TFR(29) TFR(16) TFR(24)
    x0 += K2; x1 += K0 + 2u;
    TFR(13) TFR(15) TFR(26) TFR(6)
    x0 += K0; x1 += K1 + 3u;
    TFR(17) TFR(29) TFR(16) TFR(24)
    x0 += K1; x1 += K2 + 4u;
    TFR(13) TFR(15) TFR(26) TFR(6)
    x0 += K2; x1 += K0 + 5u;
#undef TFR
}

__device__ __forceinline__ float fast_tanh(float x) {
    const float e2 = __expf(x + x);
    const float r  = __builtin_amdgcn_rcpf(e2 + 1.0f);
    return fmaf(-2.0f, r, 1.0f);                  // 1 - 2/(e^{2x}+1)
}

__global__ __launch_bounds__(256)
void diffgait_kernel(const float* __restrict__ skes,
                     const float* __restrict__ silT,
                     const float* __restrict__ wskes,
                     const float* __restrict__ wsil_p,
                     const float* __restrict__ tsc_p,
                     float* __restrict__ out) {
    // per-k table: [A, temb, c1, e, k0', k1', k2', pad]
    __shared__ __align__(16) uint32_t tab[NSTEP][8];

    const float wsil = wsil_p[0];
    const float tsc  = tsc_p[0];

    // ---- build per-step constants + folded keys (once per block) ----
    for (int k = (int)threadIdx.x; k < NSTEP; k += 256) {
        const int t = 999 - k;                   // reversed schedule
        const float at  = ALPH.a[t + 1];
        const float atn = ALPH.a[t];
        const float c1 = 0.1f * sqrtf((1.0f - at / atn) * (1.0f - atn) / (1.0f - at));
        const float c2 = sqrtf(fmaxf(1.0f - atn - c1 * c1, 0.0f));
        const float rs = 1.0f / sqrtf(1.0f - at);
        const float A  = sqrtf(atn) - c2 * sqrtf(at) * rs;
        const float e  = c2 * rs;
        const float temb = tsc * ((float)t / 1000.0f);
        // fold_in(key(42), t): threefry((0,42), (0,t))
        uint32_t x0 = 0u, x1 = (uint32_t)t;
        tf20(0u, 42u, 0x1BD11BDAu ^ 42u, x0, x1);
        tab[k][0] = __float_as_uint(A);
        tab[k][1] = __float_as_uint(temb);
        tab[k][2] = __float_as_uint(c1);
        tab[k][3] = __float_as_uint(e);
        tab[k][4] = x0;
        tab[k][5] = x1;
        tab[k][6] = x0 ^ x1 ^ 0x1BD11BDAu;
        tab[k][7] = 0u;
    }
    __syncthreads();

    const int j  = (int)(blockIdx.x * 256u + threadIdx.x);
    const int ns = j / HW;
    const int hw = j - ns * HW;
    const int n  = ns >> 3;
    const int ss = ns & 7;
    // skes (2,3,8,64,44): flat = ((n*3+c)*8+ss)*HW + hw
    const float* sk = skes + (size_t)((n * 3) * 8 + ss) * HW + hw;
    const float w0 = wskes[0], w1 = wskes[1], w2 = wskes[2];
    const float cond = fmaf(w2, sk[2 * 8 * HW], fmaf(w1, sk[8 * HW], w0 * sk[0]));

    const float sT = silT[j];
    float sil = sT;
    float* op = out + j;
    const uint32_t cnt = (uint32_t)j;

#pragma unroll 2
    for (int k = 0; k < NSTEP; ++k) {
        const uint4 ta = *(const uint4*)&tab[k][0];
        const uint4 tb = *(const uint4*)&tab[k][4];
        const float A    = __uint_as_float(ta.x);
        const float temb = __uint_as_float(ta.y);
        const float c1   = __uint_as_float(ta.z);
        const float e    = __uint_as_float(ta.w);

        // partitionable threefry bits: counts (hi,lo) = (0, j); bits = x0 ^ x1
        uint32_t x0 = 0u, x1 = cnt;
        tf20(tb.x, tb.y, tb.z, x0, x1);
        const uint32_t bits = x0 ^ x1;

        // XLA uniform in [lo, 1): f in [1,2) -> u = f2*2 - 0.99999994
        const float f2 = __uint_as_float((bits >> 9) | 0x3F800000u) - 1.0f;
        const float u  = f2 * 2.0f - 0.99999994f;

        // XLA/Giles erfinv (f32)
        const float t1 = (1.0f - u) * (1.0f + u);          // 1 - u^2, no cancellation
        const float w  = __log2f(t1) * -0.6931472f;        // -ln(1-u^2)
        const bool  lt = w < 5.0f;
        const float ww = lt ? (w - 2.5f) : (sqrtf(w) - 3.0f);
        float p =          lt ?  2.81022636e-08f : -0.000200214257f;
        p = fmaf(p, ww,    lt ?  3.43273939e-07f :  0.000100950558f);
        p = fmaf(p, ww,    lt ? -3.5233877e-06f  :  0.00134934322f);
        p = fmaf(p, ww,    lt ? -4.39150654e-06f : -0.00367342844f);
        p = fmaf(p, ww,    lt ?  0.00021858087f  :  0.00573950773f);
        p = fmaf(p, ww,    lt ? -0.00125372503f  : -0.0076224613f);
        p = fmaf(p, ww,    lt ? -0.00417768164f  :  0.00943887047f);
        p = fmaf(p, ww,    lt ?  0.246640727f    :  1.00167406f);
        p = fmaf(p, ww,    lt ?  1.50140941f     :  2.83297682f);
        const float noise = 1.4142135f * (p * u);          // sqrt(2)*erfinv(u)

        const float d  = fmaf(c1, noise, e * sT);
        const float s0 = fast_tanh(fmaf(wsil, sil, cond) + temb);
        *op = s0; op += NELEM;
        sil = fmaf(A, s0, d);
    }
}

extern "C" void kernel_launch(void* const* d_in, const int* in_sizes, int n_in,
                              void* d_out, int out_size, void* d_ws, size_t ws_size,
                              hipStream_t stream) {
    const float* skes = (const float*)d_in[0];
    const float* silT = (const float*)d_in[1];
    const float* wsk  = (const float*)d_in[2];
    const float* wsil = (const float*)d_in[3];
    const float* tsc  = (const float*)d_in[4];
    float* out = (float*)d_out;
    (void)in_sizes; (void)n_in; (void)out_size; (void)d_ws; (void)ws_size;

    dim3 grid(NELEM / 256), block(256);
    hipLaunchKernelGGL(diffgait_kernel, grid, block, 0, stream,
                       skes, silT, wsk, wsil, tsc, out);
}